// Round 1
// baseline (7723.453 us; speedup 1.0000x reference)
//
#include <hip/hip_runtime.h>
#include <math.h>

#define BH 8
#define CCH 256
#define DCH 128
#define HH 128
#define WW 128
#define HW (HH*WW)            // 16384
#define OUT_FEAT_N (BH*CCH*HW)   // 33554432
#define NH_N (BH*DCH*HW)         // 16777216

// ---------------------------------------------------------------------------
// coordinate embedding: ce[d][pos] for pos in [0,HW), batch-independent
// ---------------------------------------------------------------------------
__global__ __launch_bounds__(128) void ce_kernel(
        const float* __restrict__ w1, const float* __restrict__ b1,
        const float* __restrict__ w2, const float* __restrict__ b2,
        float* __restrict__ ce) {
    __shared__ float h1[64];
    int pos = blockIdx.x;                 // 0..16383
    int h = pos >> 7, w = pos & 127;
    float xc = -1.0f + 2.0f * (float)w / 127.0f;
    float yc = -1.0f + 2.0f * (float)h / 127.0f;
    float c0 = xc, c1 = yc, c2 = xc * 128.0f, c3 = yc * 128.0f;
    int t = threadIdx.x;
    if (t < 64) {
        float a = c0 * w1[t*4+0] + c1 * w1[t*4+1] + c2 * w1[t*4+2] + c3 * w1[t*4+3] + b1[t];
        h1[t] = fmaxf(a, 0.0f);
    }
    __syncthreads();
    float acc = b2[t];
    #pragma unroll 8
    for (int j = 0; j < 64; ++j) acc = fmaf(h1[j], w2[t*64 + j], acc);
    ce[(size_t)t * HW + pos] = acc;
}

// ---------------------------------------------------------------------------
// conv1: [B,256,H,W] -> y1 [B,128,H,W]  (3x3 SAME, + bias)
// block: (h, d-chunk of 8, b), 128 threads = w row
// ---------------------------------------------------------------------------
__global__ __launch_bounds__(128) void conv1_kernel(
        const float* __restrict__ x, const float* __restrict__ wgt,
        const float* __restrict__ bias, float* __restrict__ y) {
    int w  = threadIdx.x;
    int h  = blockIdx.x;
    int d0 = blockIdx.y * 8;
    int b  = blockIdx.z;
    float acc[8];
    #pragma unroll
    for (int i = 0; i < 8; ++i) acc[i] = bias[d0 + i];
    const float* xb = x + (size_t)b * CCH * HW;
    for (int c = 0; c < CCH; ++c) {
        const float* xc = xb + (size_t)c * HW;
        const float* wc = wgt + ((size_t)d0 * CCH + c) * 9;
        #pragma unroll
        for (int kh = 0; kh < 3; ++kh) {
            int r = h + kh - 1;
            if (r < 0 || r >= HH) continue;     // uniform branch
            const float* xr = xc + r * WW;
            float xm = (w > 0)        ? xr[w-1] : 0.0f;
            float x0 = xr[w];
            float xp = (w < WW-1)     ? xr[w+1] : 0.0f;
            #pragma unroll
            for (int i = 0; i < 8; ++i) {
                const float* wp = wc + (size_t)i * CCH * 9 + kh * 3;
                acc[i] = fmaf(xm, wp[0], acc[i]);
                acc[i] = fmaf(x0, wp[1], acc[i]);
                acc[i] = fmaf(xp, wp[2], acc[i]);
            }
        }
    }
    float* yp = y + ((size_t)(b * DCH + d0)) * HW + h * WW + w;
    #pragma unroll
    for (int i = 0; i < 8; ++i) yp[(size_t)i * HW] = acc[i];
}

// ---------------------------------------------------------------------------
// GroupNorm stats: one block per (b,g); group channels are contiguous
// ---------------------------------------------------------------------------
__global__ __launch_bounds__(256) void gn_stats_kernel(
        const float* __restrict__ y, float* __restrict__ stats) {
    int bg = blockIdx.x;                        // 0..63
    int t = threadIdx.x;
    const float4* p = (const float4*)(y + (size_t)bg * 16 * HW);
    const int n4 = 16 * HW / 4;                 // 65536
    float s = 0.0f, ss = 0.0f;
    for (int i = t; i < n4; i += 256) {
        float4 v = p[i];
        s  += v.x + v.y + v.z + v.w;
        ss += v.x*v.x + v.y*v.y + v.z*v.z + v.w*v.w;
    }
    __shared__ float sb[256], ssb[256];
    sb[t] = s; ssb[t] = ss;
    __syncthreads();
    for (int o = 128; o > 0; o >>= 1) {
        if (t < o) { sb[t] += sb[t+o]; ssb[t] += ssb[t+o]; }
        __syncthreads();
    }
    if (t == 0) {
        float inv_n = 1.0f / (16.0f * HW);
        float mean = sb[0] * inv_n;
        float var  = ssb[0] * inv_n - mean * mean;
        stats[bg*2]   = mean;
        stats[bg*2+1] = rsqrtf(var + 1e-5f);
    }
}

// ---------------------------------------------------------------------------
// GN apply + exact GELU, in-place on y1
// ---------------------------------------------------------------------------
__global__ __launch_bounds__(256) void gn_gelu_kernel(
        float* __restrict__ y, const float* __restrict__ stats,
        const float* __restrict__ scale, const float* __restrict__ bias) {
    size_t i = (size_t)blockIdx.x * 256 + threadIdx.x;   // float4 index
    size_t e = i * 4;
    int d  = (int)((e >> 14) & 127);
    int bg = (int)(e >> 18);
    float mean = stats[bg*2], rstd = stats[bg*2+1];
    float a = rstd * scale[d];
    float c = bias[d] - mean * a;
    float4* p = (float4*)y;
    float4 v = p[i];
    float vv[4] = {v.x, v.y, v.z, v.w};
    #pragma unroll
    for (int j = 0; j < 4; ++j) {
        float t = vv[j] * a + c;
        vv[j] = 0.5f * t * (1.0f + erff(t * 0.70710678118654752f));
    }
    p[i] = make_float4(vv[0], vv[1], vv[2], vv[3]);
}

// ---------------------------------------------------------------------------
// GRU: per-position gates. Tile: 64 positions x 32 d per block, 256 threads.
// Thread microtile: 2 pos x 4 d, 6 accumulator sets (ir,iz,in,hr,hz,hn).
// X chunks (K=384: spatial|ce|hprev) and weight chunks staged in LDS.
// ---------------------------------------------------------------------------
__global__ __launch_bounds__(256) void gru_kernel(
        const float* __restrict__ spatial, const float* __restrict__ ce,
        const float* __restrict__ hprev,
        const float* __restrict__ w_ih, const float* __restrict__ b_ih,
        const float* __restrict__ w_hh, const float* __restrict__ b_hh,
        float* __restrict__ hnew) {
    __shared__ float Xs[32 * 64];        // [kk][p]
    __shared__ float Ws[3 * 32 * 36];    // [g][kk][dd] pad 36
    __shared__ float Whs[3 * 32 * 36];

    int tid  = threadIdx.x;
    int pos0 = blockIdx.x * 64;
    int b    = pos0 >> 14;
    int hw0  = pos0 & (HW - 1);
    int dbase = blockIdx.y * 32;
    int tp = tid & 31;                   // position sub-tile
    int td = tid >> 5;                   // 0..7, d sub-tile
    int d0 = dbase + td * 4;

    float air[2][4] = {}, aiz[2][4] = {}, ain[2][4] = {};
    float ahr[2][4] = {}, ahz[2][4] = {}, ahn[2][4] = {};

    for (int ck = 0; ck < 12; ++ck) {
        int k0 = ck * 32;
        __syncthreads();
        // ---- stage X chunk (32 k x 64 pos), coalesced
        const float* src;
        if (k0 < 128)       src = spatial + ((size_t)b * DCH + k0) * HW + hw0;
        else if (k0 < 256)  src = ce + (size_t)(k0 - 128) * HW + hw0;
        else                src = hprev + ((size_t)b * DCH + (k0 - 256)) * HW + hw0;
        #pragma unroll
        for (int i = 0; i < 8; ++i) {
            int idx = tid + i * 256;
            int kk = idx >> 6, p = idx & 63;
            Xs[kk * 64 + p] = src[(size_t)kk * HW + p];
        }
        // ---- stage w_ih chunk: rows g*128+dbase+dd, cols k0..k0+31
        #pragma unroll
        for (int i = 0; i < 12; ++i) {
            int idx = tid + i * 256;          // 0..3071
            int g = idx >> 10, rem = idx & 1023;
            int dd = rem >> 5, kk = rem & 31; // consecutive tid -> consecutive k (coalesced)
            Ws[(g * 32 + kk) * 36 + dd] =
                w_ih[((size_t)(g * 128 + dbase + dd)) * 384 + k0 + kk];
        }
        if (k0 >= 256) {
            #pragma unroll
            for (int i = 0; i < 12; ++i) {
                int idx = tid + i * 256;
                int g = idx >> 10, rem = idx & 1023;
                int dd = rem >> 5, kk = rem & 31;
                Whs[(g * 32 + kk) * 36 + dd] =
                    w_hh[((size_t)(g * 128 + dbase + dd)) * 128 + (k0 - 256) + kk];
            }
        }
        __syncthreads();
        // ---- compute
        if (k0 < 256) {
            for (int kk = 0; kk < 32; ++kk) {
                float2 xv = *(const float2*)&Xs[kk * 64 + 2 * tp];
                const float* wr = &Ws[(0 * 32 + kk) * 36 + 4 * td];
                const float* wz = &Ws[(1 * 32 + kk) * 36 + 4 * td];
                const float* wn = &Ws[(2 * 32 + kk) * 36 + 4 * td];
                #pragma unroll
                for (int i = 0; i < 4; ++i) {
                    float a = wr[i], z = wz[i], n = wn[i];
                    air[0][i] = fmaf(xv.x, a, air[0][i]); air[1][i] = fmaf(xv.y, a, air[1][i]);
                    aiz[0][i] = fmaf(xv.x, z, aiz[0][i]); aiz[1][i] = fmaf(xv.y, z, aiz[1][i]);
                    ain[0][i] = fmaf(xv.x, n, ain[0][i]); ain[1][i] = fmaf(xv.y, n, ain[1][i]);
                }
            }
        } else {
            for (int kk = 0; kk < 32; ++kk) {
                float2 xv = *(const float2*)&Xs[kk * 64 + 2 * tp];
                const float* wr = &Ws[(0 * 32 + kk) * 36 + 4 * td];
                const float* wz = &Ws[(1 * 32 + kk) * 36 + 4 * td];
                const float* wn = &Ws[(2 * 32 + kk) * 36 + 4 * td];
                const float* vr = &Whs[(0 * 32 + kk) * 36 + 4 * td];
                const float* vz = &Whs[(1 * 32 + kk) * 36 + 4 * td];
                const float* vn = &Whs[(2 * 32 + kk) * 36 + 4 * td];
                #pragma unroll
                for (int i = 0; i < 4; ++i) {
                    float a = wr[i], z = wz[i], n = wn[i];
                    float ha = vr[i], hz = vz[i], hn = vn[i];
                    air[0][i] = fmaf(xv.x, a, air[0][i]); air[1][i] = fmaf(xv.y, a, air[1][i]);
                    aiz[0][i] = fmaf(xv.x, z, aiz[0][i]); aiz[1][i] = fmaf(xv.y, z, aiz[1][i]);
                    ain[0][i] = fmaf(xv.x, n, ain[0][i]); ain[1][i] = fmaf(xv.y, n, ain[1][i]);
                    ahr[0][i] = fmaf(xv.x, ha, ahr[0][i]); ahr[1][i] = fmaf(xv.y, ha, ahr[1][i]);
                    ahz[0][i] = fmaf(xv.x, hz, ahz[0][i]); ahz[1][i] = fmaf(xv.y, hz, ahz[1][i]);
                    ahn[0][i] = fmaf(xv.x, hn, ahn[0][i]); ahn[1][i] = fmaf(xv.y, hn, ahn[1][i]);
                }
            }
        }
    }
    // ---- epilogue: gates + h_new
    #pragma unroll
    for (int p = 0; p < 2; ++p) {
        int pos = hw0 + 2 * tp + p;
        #pragma unroll
        for (int i = 0; i < 4; ++i) {
            int d = d0 + i;
            float ir  = air[p][i] + b_ih[d];
            float iz  = aiz[p][i] + b_ih[128 + d];
            float in_ = ain[p][i] + b_ih[256 + d];
            float hr  = ahr[p][i] + b_hh[d];
            float hz  = ahz[p][i] + b_hh[128 + d];
            float hn  = ahn[p][i] + b_hh[256 + d];
            float r = 1.0f / (1.0f + expf(-(ir + hr)));
            float z = 1.0f / (1.0f + expf(-(iz + hz)));
            float n = tanhf(in_ + r * hn);
            float hp = hprev[((size_t)b * DCH + d) * HW + pos];
            hnew[((size_t)b * DCH + d) * HW + pos] = (1.0f - z) * n + z * hp;
        }
    }
}

// ---------------------------------------------------------------------------
// conv2: new_hidden [B,128,H,W] -> [B,256,H,W], + bias + residual
// ---------------------------------------------------------------------------
__global__ __launch_bounds__(128) void conv2_kernel(
        const float* __restrict__ x, const float* __restrict__ wgt,
        const float* __restrict__ bias, const float* __restrict__ resid,
        float* __restrict__ y) {
    int w  = threadIdx.x;
    int h  = blockIdx.x;
    int c0 = blockIdx.y * 8;
    int b  = blockIdx.z;
    float acc[8];
    #pragma unroll
    for (int i = 0; i < 8; ++i) acc[i] = bias[c0 + i];
    const float* xb = x + (size_t)b * DCH * HW;
    for (int c = 0; c < DCH; ++c) {
        const float* xc = xb + (size_t)c * HW;
        const float* wc = wgt + ((size_t)c0 * DCH + c) * 9;
        #pragma unroll
        for (int kh = 0; kh < 3; ++kh) {
            int r = h + kh - 1;
            if (r < 0 || r >= HH) continue;
            const float* xr = xc + r * WW;
            float xm = (w > 0)    ? xr[w-1] : 0.0f;
            float x0 = xr[w];
            float xp = (w < WW-1) ? xr[w+1] : 0.0f;
            #pragma unroll
            for (int i = 0; i < 8; ++i) {
                const float* wp = wc + (size_t)i * DCH * 9 + kh * 3;
                acc[i] = fmaf(xm, wp[0], acc[i]);
                acc[i] = fmaf(x0, wp[1], acc[i]);
                acc[i] = fmaf(xp, wp[2], acc[i]);
            }
        }
    }
    size_t base = ((size_t)(b * CCH + c0)) * HW + h * WW + w;
    #pragma unroll
    for (int i = 0; i < 8; ++i)
        y[base + (size_t)i * HW] = acc[i] + resid[base + (size_t)i * HW];
}

// ---------------------------------------------------------------------------
extern "C" void kernel_launch(void* const* d_in, const int* in_sizes, int n_in,
                              void* d_out, int out_size, void* d_ws, size_t ws_size,
                              hipStream_t stream) {
    const float* current_feat = (const float*)d_in[0];
    const float* prev_hidden  = (const float*)d_in[1];
    const float* conv1_w = (const float*)d_in[2];
    const float* conv1_b = (const float*)d_in[3];
    const float* gn_scale = (const float*)d_in[4];
    const float* gn_bias  = (const float*)d_in[5];
    const float* ce_w1 = (const float*)d_in[6];
    const float* ce_b1 = (const float*)d_in[7];
    const float* ce_w2 = (const float*)d_in[8];
    const float* ce_b2 = (const float*)d_in[9];
    const float* w_ih = (const float*)d_in[10];
    const float* b_ih = (const float*)d_in[11];
    const float* w_hh = (const float*)d_in[12];
    const float* b_hh = (const float*)d_in[13];
    const float* conv2_w = (const float*)d_in[14];
    const float* conv2_b = (const float*)d_in[15];

    float* ws = (float*)d_ws;
    float* y1    = ws;                     // 16777216 floats (64 MB)
    float* ce    = ws + 16777216;          // 2097152 floats (8 MB)
    float* stats = ws + 18874368;          // 128 floats
    float* out_feat  = (float*)d_out;
    float* new_hidden = out_feat + OUT_FEAT_N;

    hipLaunchKernelGGL(ce_kernel, dim3(HW), dim3(128), 0, stream,
                       ce_w1, ce_b1, ce_w2, ce_b2, ce);
    hipLaunchKernelGGL(conv1_kernel, dim3(HH, DCH/8, BH), dim3(128), 0, stream,
                       current_feat, conv1_w, conv1_b, y1);
    hipLaunchKernelGGL(gn_stats_kernel, dim3(64), dim3(256), 0, stream, y1, stats);
    hipLaunchKernelGGL(gn_gelu_kernel, dim3(NH_N/4/256), dim3(256), 0, stream,
                       y1, stats, gn_scale, gn_bias);
    hipLaunchKernelGGL(gru_kernel, dim3((BH*HW)/64, 4), dim3(256), 0, stream,
                       y1, ce, prev_hidden, w_ih, b_ih, w_hh, b_hh, new_hidden);
    hipLaunchKernelGGL(conv2_kernel, dim3(HH, CCH/8, BH), dim3(128), 0, stream,
                       new_hidden, conv2_w, conv2_b, current_feat, out_feat);
}

// Round 3
// 1126.690 us; speedup vs baseline: 6.8550x; 6.8550x over previous
//
#include <hip/hip_runtime.h>
#include <math.h>

#define BH 8
#define HH 128
#define WW 128
#define HW 16384

typedef __attribute__((ext_vector_type(8))) short bf16x8;
typedef __attribute__((ext_vector_type(4))) float f32x4;

__device__ inline unsigned short f2bf(float f) {
    union { float f; unsigned u; } v; v.f = f;
    unsigned r = v.u + 0x7FFF + ((v.u >> 16) & 1);
    return (unsigned short)(r >> 16);
}
__device__ inline float bf2f(unsigned short u) {
    union { unsigned u; float f; } v; v.u = (unsigned)u << 16;
    return v.f;
}

// ---------------------------------------------------------------------------
// transpose+cast: [B][C][HW] f32 -> [B][HW][C] bf16   (32c x 64pos tiles)
// ---------------------------------------------------------------------------
__global__ __launch_bounds__(256) void transpose_cast(
        const float* __restrict__ in, unsigned short* __restrict__ out, int C) {
    __shared__ float T[32][65];
    int tid = threadIdx.x;
    int pb = blockIdx.x * 64, cb = blockIdx.y * 32, b = blockIdx.z;
    #pragma unroll
    for (int j = 0; j < 8; ++j) {
        int idx = tid + j * 256;
        int c = idx >> 6, p = idx & 63;
        T[c][p] = in[((size_t)(b * C + cb + c)) * HW + pb + p];
    }
    __syncthreads();
    #pragma unroll
    for (int j = 0; j < 8; ++j) {
        int idx = tid + j * 256;
        int p = idx >> 5, c = idx & 31;
        out[((size_t)(b * HW + pb + p)) * C + cb + c] = f2bf(T[c][p]);
    }
}

// ---------------------------------------------------------------------------
// weight repack to bf16:
//   w1t[t][d][c]   (t=kh*3+kw)        9*128*256
//   w2t[t][co][ci]                    9*256*128
//   wg[m][k] m<512,k<384: K = [spatial | h(wih) | h(whh)], ce moved to fp32.
//     rows: 0-127 r_comb, 128-255 z_comb, 256-383 i_n (whh part 0),
//           384-511 h_n (wih parts 0)
// ---------------------------------------------------------------------------
__global__ __launch_bounds__(256) void repack_weights(
        const float* __restrict__ w1, const float* __restrict__ w2,
        const float* __restrict__ wih, const float* __restrict__ whh,
        unsigned short* __restrict__ w1t, unsigned short* __restrict__ w2t,
        unsigned short* __restrict__ wg) {
    int i = blockIdx.x * 256 + threadIdx.x;
    if (i < 294912) {
        int t = i >> 15, rem = i & 32767, d = rem >> 8, c = rem & 255;
        w1t[i] = f2bf(w1[((size_t)(d * 256 + c)) * 9 + t]);
    }
    if (i < 294912) {
        int t = i >> 15, co = (i >> 7) & 255, ci = i & 127;
        w2t[i] = f2bf(w2[((size_t)(co * 128 + ci)) * 9 + t]);
    }
    if (i < 196608) {
        int m = i / 384, k = i - m * 384;
        float v = 0.0f;
        if (m < 384) {          // r_comb / z_comb / i_n rows use wih row m
            if (k < 128)       v = wih[(size_t)m * 384 + k];
            else if (k < 256)  v = wih[(size_t)m * 384 + 256 + (k - 128)];
            else               v = (m < 256) ? whh[(size_t)m * 128 + (k - 256)] : 0.0f;
        } else {                // h_n rows: whh row m-128 (= 256 + (m-384))
            v = (k >= 256) ? whh[(size_t)(m - 128) * 128 + (k - 256)] : 0.0f;
        }
        wg[i] = f2bf(v);
    }
}

// ---------------------------------------------------------------------------
// prep_ce: M[j][m] = sum_d w2[d][j] * wih[m][128+d]   (64 x 384, fp32)
//          cebias[m] = sum_d b2[d] * wih[m][128+d]
// ---------------------------------------------------------------------------
__global__ __launch_bounds__(256) void prep_ce(
        const float* __restrict__ w2, const float* __restrict__ b2,
        const float* __restrict__ wih,
        float* __restrict__ M, float* __restrict__ cebias) {
    int i = blockIdx.x * 256 + threadIdx.x;
    if (i < 24576) {
        int j = i / 384, m = i - j * 384;
        float acc = 0.0f;
        for (int d = 0; d < 128; ++d)
            acc = fmaf(w2[(size_t)d * 64 + j], wih[(size_t)m * 384 + 128 + d], acc);
        M[i] = acc;
    } else if (i < 24960) {
        int m = i - 24576;
        float acc = 0.0f;
        for (int d = 0; d < 128; ++d)
            acc = fmaf(b2[d], wih[(size_t)m * 384 + 128 + d], acc);
        cebias[m] = acc;
    }
}

// ---------------------------------------------------------------------------
// ce_g[pos][384] fp32 = relu(coord @ w1^T + b1) @ M + cebias
// block: 16 positions x 384 threads (thread = output m)
// ---------------------------------------------------------------------------
__global__ __launch_bounds__(384) void ce_g_kernel(
        const float* __restrict__ w1, const float* __restrict__ b1,
        const float* __restrict__ M, const float* __restrict__ cebias,
        float* __restrict__ ce_g) {
    __shared__ float h1[16][64];
    int m = threadIdx.x;
    int pos0 = blockIdx.x * 16;
    for (int e = m; e < 1024; e += 384) {
        int p = e >> 6, j = e & 63;
        int pos = pos0 + p;
        int hh = pos >> 7, wp = pos & 127;
        float xc = -1.0f + 2.0f * (float)wp / 127.0f;
        float yc = -1.0f + 2.0f * (float)hh / 127.0f;
        float a = xc * w1[j*4+0] + yc * w1[j*4+1]
                + xc * 128.0f * w1[j*4+2] + yc * 128.0f * w1[j*4+3] + b1[j];
        h1[p][j] = fmaxf(a, 0.0f);
    }
    __syncthreads();
    float acc[16];
    float cb = cebias[m];
    #pragma unroll
    for (int p = 0; p < 16; ++p) acc[p] = cb;
    for (int j = 0; j < 64; ++j) {
        float Mv = M[(size_t)j * 384 + m];
        #pragma unroll
        for (int p = 0; p < 16; ++p)
            acc[p] = fmaf(h1[p][j], Mv, acc[p]);
    }
    #pragma unroll
    for (int p = 0; p < 16; ++p)
        ce_g[(size_t)(pos0 + p) * 384 + m] = acc[p];
}

// ---------------------------------------------------------------------------
// MFMA conv (3x3 SAME) as 9 shifted GEMMs. (unchanged from round 2)
// ---------------------------------------------------------------------------
template<int CIN, int COUT, bool CONV1>
__global__ __launch_bounds__(256) void conv_mfma(
        const unsigned short* __restrict__ xt,
        const unsigned short* __restrict__ wt,
        const float* __restrict__ bias,
        float* __restrict__ stats_acc,
        const float* __restrict__ resid,
        unsigned short* __restrict__ y_bf,
        float* __restrict__ y_f32) {
    __shared__ unsigned short Ash[130 * 40];
    __shared__ unsigned short Wsh[3 * 128 * 40];

    const int tid = threadIdx.x;
    const int h = blockIdx.x, b = blockIdx.y;
    const int cobase = blockIdx.z * 128;
    const int lane = tid & 63, wave = tid >> 6;
    const int wn = (wave & 1) * 64, wd = (wave >> 1) * 64;
    const int l15 = lane & 15, quad = lane >> 4;
    const int kb = quad * 8;

    f32x4 acc[4][4];
    #pragma unroll
    for (int i = 0; i < 4; ++i)
        #pragma unroll
        for (int j = 0; j < 4; ++j)
            acc[i][j] = (f32x4){0.f, 0.f, 0.f, 0.f};

    for (int kh = 0; kh < 3; ++kh) {
        int r = h + kh - 1;
        if (r < 0 || r >= HH) continue;                   // uniform
        const unsigned short* xrow = xt + ((size_t)(b * HW + r * WW)) * CIN;
        for (int cc = 0; cc < CIN / 32; ++cc) {
            int c0 = cc * 32;
            __syncthreads();
            #pragma unroll
            for (int j = 0; j < 9; ++j) {
                int idx = tid + j * 256;
                if (idx < 2080) {
                    int i = idx >> 4, cp = (idx & 15) * 2;
                    unsigned int val = 0;
                    if (i >= 1 && i <= 128)
                        val = *(const unsigned int*)(xrow + (size_t)(i - 1) * CIN + c0 + cp);
                    *(unsigned int*)&Ash[i * 40 + cp] = val;
                }
            }
            #pragma unroll
            for (int j = 0; j < 12; ++j) {
                int idx = tid + j * 256;
                int kw = idx >> 10;
                int rem = idx & 1023;
                int d = rem >> 3, kq = (rem & 7) * 4;
                int t = kh * 3 + kw;
                const unsigned short* wp =
                    wt + ((size_t)t * COUT + cobase + d) * CIN + c0 + kq;
                *(ushort4*)&Wsh[(kw * 128 + d) * 40 + kq] = *(const ushort4*)wp;
            }
            __syncthreads();
            #pragma unroll
            for (int kw = 0; kw < 3; ++kw) {
                bf16x8 a[4], bb[4];
                #pragma unroll
                for (int fn = 0; fn < 4; ++fn)
                    a[fn] = *(const bf16x8*)&Ash[(wn + fn * 16 + l15 + kw) * 40 + kb];
                #pragma unroll
                for (int fd = 0; fd < 4; ++fd)
                    bb[fd] = *(const bf16x8*)&Wsh[(kw * 128 + wd + fd * 16 + l15) * 40 + kb];
                #pragma unroll
                for (int fn = 0; fn < 4; ++fn)
                    #pragma unroll
                    for (int fd = 0; fd < 4; ++fd)
                        acc[fn][fd] = __builtin_amdgcn_mfma_f32_16x16x32_bf16(
                            a[fn], bb[fd], acc[fn][fd], 0, 0, 0);
            }
        }
    }

    if (CONV1) {
        float gsum[4] = {0.f,0.f,0.f,0.f}, gss[4] = {0.f,0.f,0.f,0.f};
        #pragma unroll
        for (int fd = 0; fd < 4; ++fd) {
            int d = wd + fd * 16 + l15;
            float bv = bias[d];
            #pragma unroll
            for (int fn = 0; fn < 4; ++fn) {
                #pragma unroll
                for (int reg = 0; reg < 4; ++reg) {
                    int n = wn + fn * 16 + quad * 4 + reg;
                    float v = acc[fn][fd][reg] + bv;
                    y_bf[((size_t)(b * HW + h * WW + n)) * 128 + d] = f2bf(v);
                    gsum[fd] += v; gss[fd] += v * v;
                }
            }
        }
        #pragma unroll
        for (int fd = 0; fd < 4; ++fd) {
            float s = gsum[fd], q = gss[fd];
            for (int o = 32; o > 0; o >>= 1) {
                s += __shfl_down(s, o);
                q += __shfl_down(q, o);
            }
            if (lane == 0) {
                int g = (wd >> 4) + fd;
                atomicAdd(&stats_acc[(b * 8 + g) * 2], s);
                atomicAdd(&stats_acc[(b * 8 + g) * 2 + 1], q);
            }
        }
    } else {
        #pragma unroll
        for (int fd = 0; fd < 4; ++fd) {
            int co = cobase + wd + fd * 16 + l15;
            float bv = bias[co];
            #pragma unroll
            for (int fn = 0; fn < 4; ++fn) {
                int n0 = wn + fn * 16 + quad * 4;
                size_t ofs = ((size_t)(b * 256 + co)) * HW + h * WW + n0;
                float4 rs = *(const float4*)(resid + ofs);
                float4 o;
                o.x = acc[fn][fd][0] + bv + rs.x;
                o.y = acc[fn][fd][1] + bv + rs.y;
                o.z = acc[fn][fd][2] + bv + rs.z;
                o.w = acc[fn][fd][3] + bv + rs.w;
                *(float4*)(y_f32 + ofs) = o;
            }
        }
    }
}

// ---------------------------------------------------------------------------
__global__ void gn_finalize(float* stats) {   // [64][2] sums -> mean,rstd
    int t = threadIdx.x;
    if (t < 64) {
        float s = stats[t*2], q = stats[t*2+1];
        const float inv = 1.0f / 262144.0f;   // 16 ch * HW
        float mean = s * inv;
        float var = q * inv - mean * mean;
        stats[t*2] = mean;
        stats[t*2+1] = rsqrtf(var + 1e-5f);
    }
}

// ---------------------------------------------------------------------------
// GN apply + exact GELU, in-place on y1t [B][HW][128] bf16 (ushort4)
// ---------------------------------------------------------------------------
__global__ __launch_bounds__(256) void gn_gelu(
        unsigned short* __restrict__ y, const float* __restrict__ stats,
        const float* __restrict__ scale, const float* __restrict__ bias) {
    size_t i = (size_t)blockIdx.x * 256 + threadIdx.x;  // ushort4 index
    size_t e = i * 4;
    int d = (int)(e & 127);
    int b = (int)(e >> 21);
    int g = b * 8 + (d >> 4);
    float mean = stats[g * 2], rstd = stats[g * 2 + 1];
    ushort4 v = *(ushort4*)&y[e];
    unsigned short vs[4] = {v.x, v.y, v.z, v.w};
    #pragma unroll
    for (int j = 0; j < 4; ++j) {
        float a = rstd * scale[d + j];
        float c = bias[d + j] - mean * a;
        float t = bf2f(vs[j]) * a + c;
        vs[j] = f2bf(0.5f * t * (1.0f + erff(t * 0.70710678118654752f)));
    }
    ushort4 o = {vs[0], vs[1], vs[2], vs[3]};
    *(ushort4*)&y[e] = o;
}

// ---------------------------------------------------------------------------
// GRU unified GEMM, K=384 ([spatial|h|h]): G[p][512] bf16
// ---------------------------------------------------------------------------
__global__ __launch_bounds__(256) void gru_gemm(
        const unsigned short* __restrict__ sp_t,
        const unsigned short* __restrict__ ph_t,
        const unsigned short* __restrict__ wg,
        unsigned short* __restrict__ G) {
    __shared__ unsigned short Xs[128 * 40];
    __shared__ unsigned short Wgs[128 * 40];
    const int tid = threadIdx.x;
    const int nt = blockIdx.x, mt = blockIdx.y;
    const size_t p0 = (size_t)nt * 128;
    const int lane = tid & 63, wave = tid >> 6;
    const int wn = (wave & 1) * 64, wm = (wave >> 1) * 64;
    const int l15 = lane & 15, quad = lane >> 4, kb = quad * 8;

    f32x4 acc[4][4];
    #pragma unroll
    for (int i = 0; i < 4; ++i)
        #pragma unroll
        for (int j = 0; j < 4; ++j)
            acc[i][j] = (f32x4){0.f, 0.f, 0.f, 0.f};

    for (int ck = 0; ck < 12; ++ck) {
        int k0 = ck * 32;
        const unsigned short* xsrc;
        if (k0 < 128)      xsrc = sp_t + p0 * 128 + k0;
        else if (k0 < 256) xsrc = ph_t + p0 * 128 + (k0 - 128);
        else               xsrc = ph_t + p0 * 128 + (k0 - 256);
        __syncthreads();
        #pragma unroll
        for (int j = 0; j < 4; ++j) {
            int idx = tid + j * 256;
            int n = idx >> 3, kq = (idx & 7) * 4;
            *(ushort4*)&Xs[n * 40 + kq] = *(const ushort4*)(xsrc + (size_t)n * 128 + kq);
        }
        #pragma unroll
        for (int j = 0; j < 4; ++j) {
            int idx = tid + j * 256;
            int m = idx >> 3, kq = (idx & 7) * 4;
            *(ushort4*)&Wgs[m * 40 + kq] =
                *(const ushort4*)(wg + ((size_t)(mt * 128 + m)) * 384 + k0 + kq);
        }
        __syncthreads();
        bf16x8 a[4], bb[4];
        #pragma unroll
        for (int fn = 0; fn < 4; ++fn)
            a[fn] = *(const bf16x8*)&Xs[(wn + fn * 16 + l15) * 40 + kb];
        #pragma unroll
        for (int fm = 0; fm < 4; ++fm)
            bb[fm] = *(const bf16x8*)&Wgs[(wm + fm * 16 + l15) * 40 + kb];
        #pragma unroll
        for (int fn = 0; fn < 4; ++fn)
            #pragma unroll
            for (int fm = 0; fm < 4; ++fm)
                acc[fn][fm] = __builtin_amdgcn_mfma_f32_16x16x32_bf16(
                    a[fn], bb[fm], acc[fn][fm], 0, 0, 0);
    }
    #pragma unroll
    for (int fm = 0; fm < 4; ++fm) {
        int m = mt * 128 + wm + fm * 16 + l15;
        #pragma unroll
        for (int fn = 0; fn < 4; ++fn)
            #pragma unroll
            for (int reg = 0; reg < 4; ++reg) {
                int n = wn + fn * 16 + quad * 4 + reg;
                G[(p0 + n) * 512 + m] = f2bf(acc[fn][fm][reg]);
            }
    }
}

// ---------------------------------------------------------------------------
// GRU gates + h_new. gates = G(bf16) + ce_g(fp32) + biases; hp read fp32.
// ---------------------------------------------------------------------------
__global__ __launch_bounds__(256) void gru_gate(
        const unsigned short* __restrict__ G,
        const float* __restrict__ ce_g,
        const float* __restrict__ b_ih, const float* __restrict__ b_hh,
        const float* __restrict__ prev_f32,
        float* __restrict__ new_hidden, unsigned short* __restrict__ hn_t) {
    __shared__ float T[128][65];
    const int tid = threadIdx.x;
    const size_t p0 = (size_t)blockIdx.x * 64;
    const int b = (int)(p0 >> 14);
    const int hw0 = (int)(p0 & (HW - 1));
    const int d = tid & 127;
    const float br  = b_ih[d]       + b_hh[d];
    const float bz  = b_ih[128 + d] + b_hh[128 + d];
    const float bin = b_ih[256 + d];
    const float bhn = b_hh[256 + d];
    for (int j = 0; j < 32; ++j) {
        int pp = (tid >> 7) + j * 2;
        size_t gbase = (p0 + pp) * 512;
        size_t cbase = (size_t)(hw0 + pp) * 384;
        float rl = bf2f(G[gbase + d])       + ce_g[cbase + d]       + br;
        float zl = bf2f(G[gbase + 128 + d]) + ce_g[cbase + 128 + d] + bz;
        float il = bf2f(G[gbase + 256 + d]) + ce_g[cbase + 256 + d] + bin;
        float hl = bf2f(G[gbase + 384 + d]) + bhn;
        float r = 1.0f / (1.0f + expf(-rl));
        float z = 1.0f / (1.0f + expf(-zl));
        float n = tanhf(il + r * hl);
        float hp = prev_f32[((size_t)(b * 128 + d)) * HW + hw0 + pp];
        float hn = (1.0f - z) * n + z * hp;
        T[d][pp] = hn;
        hn_t[(p0 + pp) * 128 + d] = f2bf(hn);
    }
    __syncthreads();
    #pragma unroll
    for (int j = 0; j < 8; ++j) {
        int idx = tid + j * 256;
        int d2 = idx >> 4, pp4 = (idx & 15) * 4;
        float4 v = { T[d2][pp4], T[d2][pp4+1], T[d2][pp4+2], T[d2][pp4+3] };
        *(float4*)&new_hidden[((size_t)(b * 128 + d2)) * HW + hw0 + pp4] = v;
    }
}

// ---------------------------------------------------------------------------
extern "C" void kernel_launch(void* const* d_in, const int* in_sizes, int n_in,
                              void* d_out, int out_size, void* d_ws, size_t ws_size,
                              hipStream_t stream) {
    const float* current_feat = (const float*)d_in[0];
    const float* prev_hidden  = (const float*)d_in[1];
    const float* conv1_w = (const float*)d_in[2];
    const float* conv1_b = (const float*)d_in[3];
    const float* gn_scale = (const float*)d_in[4];
    const float* gn_bias  = (const float*)d_in[5];
    const float* ce_w1 = (const float*)d_in[6];
    const float* ce_b1 = (const float*)d_in[7];
    const float* ce_w2 = (const float*)d_in[8];
    const float* ce_b2 = (const float*)d_in[9];
    const float* w_ih = (const float*)d_in[10];
    const float* b_ih = (const float*)d_in[11];
    const float* w_hh = (const float*)d_in[12];
    const float* b_hh = (const float*)d_in[13];
    const float* conv2_w = (const float*)d_in[14];
    const float* conv2_b = (const float*)d_in[15];

    char* ws = (char*)d_ws;
    unsigned short* cf_t = (unsigned short*)(ws);               // [0, 64Mi)
    unsigned short* ph_t = (unsigned short*)(ws + 67108864);    // [64Mi, 96Mi)
    unsigned short* sp_t = (unsigned short*)(ws + 100663296);   // [96Mi, 128Mi)
    unsigned short* w1t  = (unsigned short*)(ws + 134217728);
    unsigned short* w2t  = (unsigned short*)(ws + 134807552);
    unsigned short* wg   = (unsigned short*)(ws + 135397376);
    float* Mmat          = (float*)(ws + 135790592);            // 64x384 fp32
    float* cebias        = (float*)(ws + 135888896);            // 384 fp32
    float* stats         = (float*)(ws + 135890432);            // 128 fp32
    unsigned short* hn_t = cf_t;                                // reuse [0,32Mi)
    float* ce_g          = (float*)(ws + 33554432);             // reuse [32Mi,~56Mi)
    unsigned short* G    = (unsigned short*)d_out;              // 128 MiB scratch
    float* out_feat      = (float*)d_out;
    float* new_hidden    = (float*)d_out + 33554432;

    hipMemsetAsync(stats, 0, 512, stream);
    hipLaunchKernelGGL(repack_weights, dim3(1152), dim3(256), 0, stream,
                       conv1_w, conv2_w, w_ih, w_hh, w1t, w2t, wg);
    hipLaunchKernelGGL(prep_ce, dim3(98), dim3(256), 0, stream,
                       ce_w2, ce_b2, w_ih, Mmat, cebias);
    hipLaunchKernelGGL(transpose_cast, dim3(256, 8, 8), dim3(256), 0, stream,
                       current_feat, cf_t, 256);
    hipLaunchKernelGGL(transpose_cast, dim3(256, 4, 8), dim3(256), 0, stream,
                       prev_hidden, ph_t, 128);
    hipLaunchKernelGGL((conv_mfma<256, 128, true>), dim3(128, 8, 1), dim3(256), 0, stream,
                       cf_t, w1t, conv1_b, stats, nullptr, sp_t, nullptr);
    hipLaunchKernelGGL(ce_g_kernel, dim3(1024), dim3(384), 0, stream,
                       ce_w1, ce_b1, Mmat, cebias, ce_g);   // after conv1 (reuses cf_t space)
    hipLaunchKernelGGL(gn_finalize, dim3(1), dim3(64), 0, stream, stats);
    hipLaunchKernelGGL(gn_gelu, dim3(16384), dim3(256), 0, stream,
                       sp_t, stats, gn_scale, gn_bias);
    hipLaunchKernelGGL(gru_gemm, dim3(1024, 4), dim3(256), 0, stream,
                       sp_t, ph_t, wg, G);
    hipLaunchKernelGGL(gru_gate, dim3(2048), dim3(256), 0, stream,
                       G, ce_g, b_ih, b_hh, prev_hidden, new_hidden, hn_t);
    hipLaunchKernelGGL((conv_mfma<128, 256, false>), dim3(128, 8, 2), dim3(256), 0, stream,
                       hn_t, w2t, conv2_b, nullptr, current_feat, nullptr, out_feat);
}